// Round 12
// baseline (180.960 us; speedup 1.0000x reference)
//
#include <hip/hip_runtime.h>
#include <math.h>

#define NN 10000
#define FIN 512
#define HD 40
#define GEPS 1e-5f

#define ZI4 ((2 * NN + 2 * HD) / 4)       // 5020 int4s (cnt, cur, stats)
#define MM1_BLOCKS ((NN + 15) / 16)       // 625
#define ZERO_BLOCKS ((ZI4 + 255) / 256)   // 20

// ---------------- CSR build ----------------
__global__ void k_hist(const int* __restrict__ dst, int* __restrict__ cnt, int E) {
    int e = blockIdx.x * blockDim.x + threadIdx.x;
    if (e < E) atomicAdd(&cnt[dst[e]], 1);
}

// single block, 1024 threads; 10 rows per thread; fused dis=rsqrt(deg)
__global__ __launch_bounds__(1024) void k_scan(const int* __restrict__ cnt,
                                               int* __restrict__ rowstart,
                                               float* __restrict__ dis) {
    __shared__ int lds[1024];
    const int t = threadIdx.x;
    const int start = t * 10;
    const int end = min(start + 10, NN);
    int s = 0;
    for (int i = start; i < end; ++i) s += cnt[i];
    lds[t] = s;
    __syncthreads();
    for (int off = 1; off < 1024; off <<= 1) {
        int v = (t >= off) ? lds[t - off] : 0;
        __syncthreads();
        lds[t] += v;
        __syncthreads();
    }
    int run = lds[t] - s;   // exclusive prefix
    for (int i = start; i < end; ++i) {
        int c = cnt[i];
        rowstart[i] = run;
        run += c;
        dis[i] = rsqrtf((float)c);
    }
    if (end == NN) rowstart[NN] = run;
}

__global__ void k_fill(const int* __restrict__ src, const int* __restrict__ dst,
                       const int* __restrict__ rowstart, int* __restrict__ cur,
                       const float* __restrict__ dis, int2* __restrict__ csr, int E) {
    int e = blockIdx.x * blockDim.x + threadIdx.x;
    if (e >= E) return;
    int s = src[e], d = dst[e];
    int pos = rowstart[d] + atomicAdd(&cur[d], 1);
    int2 v;
    v.x = s;
    v.y = __float_as_int(dis[s] * dis[d]);
    csr[pos] = v;
}

// ---------------- h1 = x @ W1 (16 rows x 16 kgroups; spare blocks zero cnt/cur/stats) ----------------
__global__ __launch_bounds__(256) void k_mm1z(const float* __restrict__ x,
                                              const float* __restrict__ W1,
                                              float* __restrict__ h1,
                                              int4* __restrict__ zbuf) {
    if (blockIdx.x >= MM1_BLOCKS) {       // zero-duty blocks
        int i = (blockIdx.x - MM1_BLOCKS) * 256 + threadIdx.x;
        if (i < ZI4) zbuf[i] = make_int4(0, 0, 0, 0);
        return;
    }
    __shared__ float red[256 * 41];       // 41-pad: odd stride -> conflict-free
    const int tid = threadIdx.x;
    const int r = tid & 15;
    const int kg = tid >> 4;              // 0..15, 32 k each
    const int row = blockIdx.x * 16 + r;
    const int rowc = min(row, NN - 1);
    const float4* xr = (const float4*)(x + (size_t)rowc * FIN + kg * 32);
    float acc[HD];
#pragma unroll
    for (int c = 0; c < HD; ++c) acc[c] = 0.f;
#pragma unroll 2
    for (int q = 0; q < 8; ++q) {
        float4 xv = xr[q];
        const float* wbase = W1 + (size_t)(kg * 32 + q * 4) * HD;
#pragma unroll
        for (int kk = 0; kk < 4; ++kk) {
            float xs = (kk == 0) ? xv.x : (kk == 1) ? xv.y : (kk == 2) ? xv.z : xv.w;
#pragma unroll
            for (int c4 = 0; c4 < 10; ++c4) {
                float4 wv = *(const float4*)(wbase + kk * HD + c4 * 4);
                acc[c4 * 4 + 0] = fmaf(xs, wv.x, acc[c4 * 4 + 0]);
                acc[c4 * 4 + 1] = fmaf(xs, wv.y, acc[c4 * 4 + 1]);
                acc[c4 * 4 + 2] = fmaf(xs, wv.z, acc[c4 * 4 + 2]);
                acc[c4 * 4 + 3] = fmaf(xs, wv.w, acc[c4 * 4 + 3]);
            }
        }
    }
#pragma unroll
    for (int c = 0; c < HD; ++c) red[tid * 41 + c] = acc[c];
    __syncthreads();
    if (tid < 160) {                      // 16 rows x 10 float4
        int rr = tid / 10, c4 = tid % 10;
        float o0 = 0.f, o1 = 0.f, o2 = 0.f, o3 = 0.f;
#pragma unroll
        for (int kg2 = 0; kg2 < 16; ++kg2) {
            const float* p = &red[(kg2 * 16 + rr) * 41 + c4 * 4];
            o0 += p[0]; o1 += p[1]; o2 += p[2]; o3 += p[3];
        }
        int orow = blockIdx.x * 16 + rr;
        if (orow < NN)
            *(float4*)&h1[(size_t)orow * HD + c4 * 4] = make_float4(o0, o1, o2, o3);
    }
}

// ---------------- gather: out[n] = sum coef * f(hin[src]) ----------------
// 2 threads per (node,c4) slot, each a CONTIGUOUS half of the edge range,
// 4 independent edges in flight per round (clamp+mask tail keeps MLP shape).
template <bool NORM>
__global__ __launch_bounds__(256) void k_gather(const int* __restrict__ rowstart,
                                                const int2* __restrict__ csr,
                                                const float* __restrict__ hin,
                                                const float* __restrict__ stats,
                                                const float* __restrict__ b1,
                                                const float* __restrict__ gw,
                                                const float* __restrict__ gb,
                                                const float* __restrict__ ga,
                                                float* __restrict__ aggout) {
    __shared__ float4 part[256];
    __shared__ float csc[2 * HD];
    const int t = threadIdx.x;
    if (NORM) {
        if (t < HD) {
            float m   = stats[t] * (1.0f / NN);
            float ex2 = stats[HD + t] * (1.0f / NN);
            float a   = ga[t];
            float var = ex2 - 2.0f * a * m * m + a * a * m * m;
            float sc  = gw[t] * rsqrtf(var + GEPS);
            csc[t]      = sc;
            csc[HD + t] = sc * (b1[t] - a * m) + gb[t];
        }
        __syncthreads();
    }
    const int slot = blockIdx.x * 128 + (t & 127);
    const int half = t >> 7;
    float4 acc = make_float4(0.f, 0.f, 0.f, 0.f);
    if (slot < NN * 10) {
        const int n = slot / 10, c4 = slot % 10;
        const int j0 = rowstart[n], j1 = rowstart[n + 1];
        const int mid = j0 + ((j1 - j0 + 1) >> 1);
        const int ja = half ? mid : j0;
        const int jb = half ? j1 : mid;
        float4 sc, sh;
        if (NORM) {
            sc = ((const float4*)csc)[c4];
            sh = ((const float4*)csc)[10 + c4];
        }
        for (int j = ja; j < jb; j += 4) {
            const int jm = jb - 1;
            int2 e0 = csr[j];
            int2 e1 = csr[min(j + 1, jm)];
            int2 e2 = csr[min(j + 2, jm)];
            int2 e3 = csr[min(j + 3, jm)];
            float4 v0 = *(const float4*)&hin[(size_t)e0.x * HD + c4 * 4];
            float4 v1 = *(const float4*)&hin[(size_t)e1.x * HD + c4 * 4];
            float4 v2 = *(const float4*)&hin[(size_t)e2.x * HD + c4 * 4];
            float4 v3 = *(const float4*)&hin[(size_t)e3.x * HD + c4 * 4];
            float c0 = __int_as_float(e0.y);
            float c1 = (j + 1 < jb) ? __int_as_float(e1.y) : 0.f;
            float c2 = (j + 2 < jb) ? __int_as_float(e2.y) : 0.f;
            float c3 = (j + 3 < jb) ? __int_as_float(e3.y) : 0.f;
            if (NORM) {
                v0.x = fmaxf(fmaf(sc.x, v0.x, sh.x), 0.f);
                v0.y = fmaxf(fmaf(sc.y, v0.y, sh.y), 0.f);
                v0.z = fmaxf(fmaf(sc.z, v0.z, sh.z), 0.f);
                v0.w = fmaxf(fmaf(sc.w, v0.w, sh.w), 0.f);
                v1.x = fmaxf(fmaf(sc.x, v1.x, sh.x), 0.f);
                v1.y = fmaxf(fmaf(sc.y, v1.y, sh.y), 0.f);
                v1.z = fmaxf(fmaf(sc.z, v1.z, sh.z), 0.f);
                v1.w = fmaxf(fmaf(sc.w, v1.w, sh.w), 0.f);
                v2.x = fmaxf(fmaf(sc.x, v2.x, sh.x), 0.f);
                v2.y = fmaxf(fmaf(sc.y, v2.y, sh.y), 0.f);
                v2.z = fmaxf(fmaf(sc.z, v2.z, sh.z), 0.f);
                v2.w = fmaxf(fmaf(sc.w, v2.w, sh.w), 0.f);
                v3.x = fmaxf(fmaf(sc.x, v3.x, sh.x), 0.f);
                v3.y = fmaxf(fmaf(sc.y, v3.y, sh.y), 0.f);
                v3.z = fmaxf(fmaf(sc.z, v3.z, sh.z), 0.f);
                v3.w = fmaxf(fmaf(sc.w, v3.w, sh.w), 0.f);
            }
            acc.x = fmaf(v0.x, c0, fmaf(v1.x, c1, fmaf(v2.x, c2, fmaf(v3.x, c3, acc.x))));
            acc.y = fmaf(v0.y, c0, fmaf(v1.y, c1, fmaf(v2.y, c2, fmaf(v3.y, c3, acc.y))));
            acc.z = fmaf(v0.z, c0, fmaf(v1.z, c1, fmaf(v2.z, c2, fmaf(v3.z, c3, acc.z))));
            acc.w = fmaf(v0.w, c0, fmaf(v1.w, c1, fmaf(v2.w, c2, fmaf(v3.w, c3, acc.w))));
        }
    }
    part[t] = acc;
    __syncthreads();
    if (half == 0 && slot < NN * 10) {
        float4 p2 = part[t + 128];
        acc.x += p2.x; acc.y += p2.y; acc.z += p2.z; acc.w += p2.w;
        ((float4*)aggout)[slot] = acc;
    }
}

// ---------------- GraphNorm stats over agg1 (80 blocks, c4-constant stride) ----------------
__global__ __launch_bounds__(256) void k_stats(const float* __restrict__ agg1,
                                               const float* __restrict__ b1,
                                               float* __restrict__ stats) {
    __shared__ float s0[HD], s1[HD];
    if (threadIdx.x < HD) { s0[threadIdx.x] = 0.f; s1[threadIdx.x] = 0.f; }
    __syncthreads();
    const int gid = blockIdx.x * 256 + threadIdx.x;
    const int c4 = gid % 10;          // stride 20480 % 10 == 0 -> constant per thread
    float4 bv = ((const float4*)b1)[c4];
    float4 a0 = make_float4(0.f, 0.f, 0.f, 0.f);
    float4 a1 = a0;
    for (int i4 = gid; i4 < NN * 10; i4 += 80 * 256) {
        float4 v = ((const float4*)agg1)[i4];
        v.x += bv.x; v.y += bv.y; v.z += bv.z; v.w += bv.w;
        a0.x += v.x; a0.y += v.y; a0.z += v.z; a0.w += v.w;
        a1.x = fmaf(v.x, v.x, a1.x);
        a1.y = fmaf(v.y, v.y, a1.y);
        a1.z = fmaf(v.z, v.z, a1.z);
        a1.w = fmaf(v.w, v.w, a1.w);
    }
    atomicAdd(&s0[c4 * 4 + 0], a0.x); atomicAdd(&s0[c4 * 4 + 1], a0.y);
    atomicAdd(&s0[c4 * 4 + 2], a0.z); atomicAdd(&s0[c4 * 4 + 3], a0.w);
    atomicAdd(&s1[c4 * 4 + 0], a1.x); atomicAdd(&s1[c4 * 4 + 1], a1.y);
    atomicAdd(&s1[c4 * 4 + 2], a1.z); atomicAdd(&s1[c4 * 4 + 3], a1.w);
    __syncthreads();
    if (threadIdx.x < HD) {
        atomicAdd(&stats[threadIdx.x], s0[threadIdx.x]);
        atomicAdd(&stats[HD + threadIdx.x], s1[threadIdx.x]);
    }
}

// ---------------- heads (all three in one dispatch; z selects head) ----------------
__device__ __forceinline__ float activate_rt(float z, int act) {
    if (act == 0) {                    // mean: clip(exp, 1e-5, 1e6)
        return fminf(fmaxf(__expf(z), 1e-5f), 1e6f);
    } else if (act == 1) {             // disp: clip(softplus, 1e-4, 1e4)
        float sp = fmaxf(z, 0.0f) + __logf(1.0f + __expf(-fabsf(z)));
        return fminf(fmaxf(sp, 1e-4f), 1e4f);
    }
    return __fdividef(1.0f, 1.0f + __expf(-z));   // pi: sigmoid
}

// grid (ceil(NN/64), FIN/32, 3); block = 4 waves. Wave w: 64 rows x 8 cols at
// col0 = by*32 + w*8 (readfirstlane -> wave-uniform -> W/bias via SCALAR loads).
// Thread: A-row (10 float4) in VGPRs, acc[8]; inner loop = pure v_fmac, zero
// vector-memory ops. LDS=0. 4 waves/block cover 32 cols = one 128B line/row.
__global__ __launch_bounds__(256) void k_heads3(const float* __restrict__ aggh,
                                                const float* __restrict__ Wm,
                                                const float* __restrict__ bm,
                                                const float* __restrict__ Wd,
                                                const float* __restrict__ bd,
                                                const float* __restrict__ Wp,
                                                const float* __restrict__ bp,
                                                float* __restrict__ out) {
    const int z = blockIdx.z;
    const float* W    = (z == 0) ? Wm : (z == 1) ? Wd : Wp;
    const float* bias = (z == 0) ? bm : (z == 1) ? bd : bp;
    float* o = out + (size_t)z * NN * FIN;

    const int lane = threadIdx.x & 63;
    const int wv   = threadIdx.x >> 6;                      // wave 0..3
    const int row  = blockIdx.x * 64 + lane;
    const int rowc = min(row, NN - 1);
    const int col0 = __builtin_amdgcn_readfirstlane(blockIdx.y * 32 + wv * 8);

    // A-row -> VGPRs (10 independent L2 loads in flight)
    float4 a[10];
    const float4* ap = (const float4*)(aggh + (size_t)rowc * HD);
#pragma unroll
    for (int q = 0; q < 10; ++q) a[q] = ap[q];

    float acc[8];
#pragma unroll
    for (int c = 0; c < 8; ++c) acc[c] = 0.f;

    const float* wb = W + col0;   // wave-uniform base -> scalar loads
#pragma unroll
    for (int q = 0; q < 10; ++q) {
#pragma unroll
        for (int kk = 0; kk < 4; ++kk) {
            const int k = q * 4 + kk;
            const float av = (kk == 0) ? a[q].x : (kk == 1) ? a[q].y
                           : (kk == 2) ? a[q].z : a[q].w;
            const float* wk = wb + (size_t)k * FIN;
#pragma unroll
            for (int c = 0; c < 8; ++c)
                acc[c] = fmaf(av, wk[c], acc[c]);
        }
    }

    if (row < NN) {
        float4 o0, o1;
        o0.x = activate_rt(acc[0] + bias[col0 + 0], z);
        o0.y = activate_rt(acc[1] + bias[col0 + 1], z);
        o0.z = activate_rt(acc[2] + bias[col0 + 2], z);
        o0.w = activate_rt(acc[3] + bias[col0 + 3], z);
        o1.x = activate_rt(acc[4] + bias[col0 + 4], z);
        o1.y = activate_rt(acc[5] + bias[col0 + 5], z);
        o1.z = activate_rt(acc[6] + bias[col0 + 6], z);
        o1.w = activate_rt(acc[7] + bias[col0 + 7], z);
        float* orow = o + (size_t)row * FIN + col0;
        *(float4*)(orow)     = o0;
        *(float4*)(orow + 4) = o1;
    }
}

extern "C" void kernel_launch(void* const* d_in, const int* in_sizes, int n_in,
                              void* d_out, int out_size, void* d_ws, size_t ws_size,
                              hipStream_t stream) {
    const float* x   = (const float*)d_in[0];
    const int*   src = (const int*)d_in[1];
    const int*   dst = (const int*)d_in[2];
    const float* W1  = (const float*)d_in[3];
    const float* b1  = (const float*)d_in[4];
    const float* gnw = (const float*)d_in[5];
    const float* gnb = (const float*)d_in[6];
    const float* gna = (const float*)d_in[7];
    const float* Wm  = (const float*)d_in[8];
    const float* bm  = (const float*)d_in[9];
    const float* Wd  = (const float*)d_in[10];
    const float* bd  = (const float*)d_in[11];
    const float* Wp  = (const float*)d_in[12];
    const float* bp  = (const float*)d_in[13];
    const int E = in_sizes[1];

    // workspace layout: zero-region (cnt,cur,stats) is 16B-aligned by construction
    float* ws       = (float*)d_ws;
    float* h1       = ws;                          // NN*HD  (mm1 out; later aggh)
    float* agg1     = h1 + (size_t)NN * HD;        // NN*HD  (gather1 out)
    int*   cnt      = (int*)(agg1 + (size_t)NN * HD);  // NN   } zeroed (int4)
    int*   cur      = cnt + NN;                    // NN     } zeroed
    float* stats    = (float*)(cur + NN);          // 2*HD   } zeroed
    float* dis      = stats + 2 * HD;              // NN
    int*   rowstart = (int*)(dis + NN);            // NN+1 (+1 pad for int2 align)
    int2*  csr      = (int2*)(rowstart + NN + 2);  // E int2, 8B-aligned
    float* out      = (float*)d_out;

    // mm1 + zero fused (zero blocks ride along; cnt zeroed before k_hist runs)
    k_mm1z<<<MM1_BLOCKS + ZERO_BLOCKS, 256, 0, stream>>>(x, W1, h1, (int4*)cnt);
    k_hist<<<(E + 255) / 256, 256, 0, stream>>>(dst, cnt, E);
    k_scan<<<1, 1024, 0, stream>>>(cnt, rowstart, dis);
    k_fill<<<(E + 255) / 256, 256, 0, stream>>>(src, dst, rowstart, cur, dis, csr, E);
    const int gblocks = (NN * 10 + 127) / 128;
    k_gather<false><<<gblocks, 256, 0, stream>>>(rowstart, csr, h1, nullptr,
                                                 nullptr, nullptr, nullptr, nullptr, agg1);
    k_stats<<<80, 256, 0, stream>>>(agg1, b1, stats);
    k_gather<true><<<gblocks, 256, 0, stream>>>(rowstart, csr, agg1, stats,
                                                b1, gnw, gnb, gna, h1);
    dim3 hgrid((NN + 63) / 64, FIN / 32, 3);
    k_heads3<<<hgrid, 256, 0, stream>>>(h1, Wm, bm, Wd, bd, Wp, bp, out);
}

// Round 13
// 120.305 us; speedup vs baseline: 1.5042x; 1.5042x over previous
//
#include <hip/hip_runtime.h>
#include <math.h>

#define NN 10000
#define FIN 512
#define HD 40
#define GEPS 1e-5f

#define ZI4 ((2 * NN + 2 * HD) / 4)       // 5020 int4s (cnt, cur, stats)
#define MM1_BLOCKS ((NN + 15) / 16)       // 625
#define ZERO_BLOCKS ((ZI4 + 255) / 256)   // 20

typedef _Float16 h4 __attribute__((ext_vector_type(4)));
typedef float f4 __attribute__((ext_vector_type(4)));

// ---------------- CSR build ----------------
__global__ void k_hist(const int* __restrict__ dst, int* __restrict__ cnt, int E) {
    int e = blockIdx.x * blockDim.x + threadIdx.x;
    if (e < E) atomicAdd(&cnt[dst[e]], 1);
}

// single block, 1024 threads; 10 rows per thread; fused dis=rsqrt(deg)
__global__ __launch_bounds__(1024) void k_scan(const int* __restrict__ cnt,
                                               int* __restrict__ rowstart,
                                               float* __restrict__ dis) {
    __shared__ int lds[1024];
    const int t = threadIdx.x;
    const int start = t * 10;
    const int end = min(start + 10, NN);
    int s = 0;
    for (int i = start; i < end; ++i) s += cnt[i];
    lds[t] = s;
    __syncthreads();
    for (int off = 1; off < 1024; off <<= 1) {
        int v = (t >= off) ? lds[t - off] : 0;
        __syncthreads();
        lds[t] += v;
        __syncthreads();
    }
    int run = lds[t] - s;   // exclusive prefix
    for (int i = start; i < end; ++i) {
        int c = cnt[i];
        rowstart[i] = run;
        run += c;
        dis[i] = rsqrtf((float)c);
    }
    if (end == NN) rowstart[NN] = run;
}

__global__ void k_fill(const int* __restrict__ src, const int* __restrict__ dst,
                       const int* __restrict__ rowstart, int* __restrict__ cur,
                       const float* __restrict__ dis, int2* __restrict__ csr, int E) {
    int e = blockIdx.x * blockDim.x + threadIdx.x;
    if (e >= E) return;
    int s = src[e], d = dst[e];
    int pos = rowstart[d] + atomicAdd(&cur[d], 1);
    int2 v;
    v.x = s;
    v.y = __float_as_int(dis[s] * dis[d]);
    csr[pos] = v;
}

// ---------------- W -> fp16 fragment-contiguous layout ----------------
// Whf[((z*32+ct)*3+kk)*64 + lane][j] = (k<40 ? W_z[k][ct*16 + (lane&15)] : 0)
// with k = kk*16 + (lane>>4)*4 + j    (B/A-fragment order for mfma 16x16x16f16)
__global__ void k_cvtW(const float* __restrict__ Wm, const float* __restrict__ Wd,
                       const float* __restrict__ Wp, _Float16* __restrict__ Whf) {
    int idx = blockIdx.x * 256 + threadIdx.x;    // one half4 per thread
    if (idx >= 3 * 32 * 3 * 64) return;
    int lane = idx & 63;
    int kk   = (idx >> 6) % 3;
    int ct   = ((idx >> 6) / 3) % 32;
    int z    = idx / (64 * 3 * 32);
    const float* W = (z == 0) ? Wm : (z == 1) ? Wd : Wp;
    int col = ct * 16 + (lane & 15);
    h4 v;
#pragma unroll
    for (int j = 0; j < 4; ++j) {
        int krow = kk * 16 + (lane >> 4) * 4 + j;
        v[j] = (krow < HD) ? (_Float16)W[(size_t)krow * FIN + col] : (_Float16)0.f;
    }
    *(h4*)(Whf + (size_t)idx * 4) = v;
}

// ---------------- h1 = x @ W1 (16 rows x 16 kgroups; spare blocks zero cnt/cur/stats) ----------------
__global__ __launch_bounds__(256) void k_mm1z(const float* __restrict__ x,
                                              const float* __restrict__ W1,
                                              float* __restrict__ h1,
                                              int4* __restrict__ zbuf) {
    if (blockIdx.x >= MM1_BLOCKS) {       // zero-duty blocks
        int i = (blockIdx.x - MM1_BLOCKS) * 256 + threadIdx.x;
        if (i < ZI4) zbuf[i] = make_int4(0, 0, 0, 0);
        return;
    }
    __shared__ float red[256 * 41];       // 41-pad: odd stride -> conflict-free
    const int tid = threadIdx.x;
    const int r = tid & 15;
    const int kg = tid >> 4;              // 0..15, 32 k each
    const int row = blockIdx.x * 16 + r;
    const int rowc = min(row, NN - 1);
    const float4* xr = (const float4*)(x + (size_t)rowc * FIN + kg * 32);
    float acc[HD];
#pragma unroll
    for (int c = 0; c < HD; ++c) acc[c] = 0.f;
#pragma unroll 2
    for (int q = 0; q < 8; ++q) {
        float4 xv = xr[q];
        const float* wbase = W1 + (size_t)(kg * 32 + q * 4) * HD;
#pragma unroll
        for (int kk = 0; kk < 4; ++kk) {
            float xs = (kk == 0) ? xv.x : (kk == 1) ? xv.y : (kk == 2) ? xv.z : xv.w;
#pragma unroll
            for (int c4 = 0; c4 < 10; ++c4) {
                float4 wv = *(const float4*)(wbase + kk * HD + c4 * 4);
                acc[c4 * 4 + 0] = fmaf(xs, wv.x, acc[c4 * 4 + 0]);
                acc[c4 * 4 + 1] = fmaf(xs, wv.y, acc[c4 * 4 + 1]);
                acc[c4 * 4 + 2] = fmaf(xs, wv.z, acc[c4 * 4 + 2]);
                acc[c4 * 4 + 3] = fmaf(xs, wv.w, acc[c4 * 4 + 3]);
            }
        }
    }
#pragma unroll
    for (int c = 0; c < HD; ++c) red[tid * 41 + c] = acc[c];
    __syncthreads();
    if (tid < 160) {                      // 16 rows x 10 float4
        int rr = tid / 10, c4 = tid % 10;
        float o0 = 0.f, o1 = 0.f, o2 = 0.f, o3 = 0.f;
#pragma unroll
        for (int kg2 = 0; kg2 < 16; ++kg2) {
            const float* p = &red[(kg2 * 16 + rr) * 41 + c4 * 4];
            o0 += p[0]; o1 += p[1]; o2 += p[2]; o3 += p[3];
        }
        int orow = blockIdx.x * 16 + rr;
        if (orow < NN)
            *(float4*)&h1[(size_t)orow * HD + c4 * 4] = make_float4(o0, o1, o2, o3);
    }
}

// ---------------- gather: out[n] = sum coef * f(hin[src]) ----------------
// 2 threads per (node,c4) slot, contiguous half ranges, 4 edges in flight.
// !NORM: writes f32 agg. NORM: applies relu(sc*v+sh), writes f16 [NN][48] (k 40..47 zero).
template <bool NORM>
__global__ __launch_bounds__(256) void k_gather(const int* __restrict__ rowstart,
                                                const int2* __restrict__ csr,
                                                const float* __restrict__ hin,
                                                const float* __restrict__ stats,
                                                const float* __restrict__ b1,
                                                const float* __restrict__ gw,
                                                const float* __restrict__ gb,
                                                const float* __restrict__ ga,
                                                float* __restrict__ aggout_f,
                                                _Float16* __restrict__ aggout_h) {
    __shared__ float4 part[256];
    __shared__ float csc[2 * HD];
    const int t = threadIdx.x;
    if (NORM) {
        if (t < HD) {
            float m   = stats[t] * (1.0f / NN);
            float ex2 = stats[HD + t] * (1.0f / NN);
            float a   = ga[t];
            float var = ex2 - 2.0f * a * m * m + a * a * m * m;
            float sc  = gw[t] * rsqrtf(var + GEPS);
            csc[t]      = sc;
            csc[HD + t] = sc * (b1[t] - a * m) + gb[t];
        }
        __syncthreads();
    }
    const int slot = blockIdx.x * 128 + (t & 127);
    const int half = t >> 7;
    float4 acc = make_float4(0.f, 0.f, 0.f, 0.f);
    if (slot < NN * 10) {
        const int n = slot / 10, c4 = slot % 10;
        const int j0 = rowstart[n], j1 = rowstart[n + 1];
        const int mid = j0 + ((j1 - j0 + 1) >> 1);
        const int ja = half ? mid : j0;
        const int jb = half ? j1 : mid;
        float4 sc, sh;
        if (NORM) {
            sc = ((const float4*)csc)[c4];
            sh = ((const float4*)csc)[10 + c4];
        }
        for (int j = ja; j < jb; j += 4) {
            const int jm = jb - 1;
            int2 e0 = csr[j];
            int2 e1 = csr[min(j + 1, jm)];
            int2 e2 = csr[min(j + 2, jm)];
            int2 e3 = csr[min(j + 3, jm)];
            float4 v0 = *(const float4*)&hin[(size_t)e0.x * HD + c4 * 4];
            float4 v1 = *(const float4*)&hin[(size_t)e1.x * HD + c4 * 4];
            float4 v2 = *(const float4*)&hin[(size_t)e2.x * HD + c4 * 4];
            float4 v3 = *(const float4*)&hin[(size_t)e3.x * HD + c4 * 4];
            float c0 = __int_as_float(e0.y);
            float c1 = (j + 1 < jb) ? __int_as_float(e1.y) : 0.f;
            float c2 = (j + 2 < jb) ? __int_as_float(e2.y) : 0.f;
            float c3 = (j + 3 < jb) ? __int_as_float(e3.y) : 0.f;
            if (NORM) {
                v0.x = fmaxf(fmaf(sc.x, v0.x, sh.x), 0.f);
                v0.y = fmaxf(fmaf(sc.y, v0.y, sh.y), 0.f);
                v0.z = fmaxf(fmaf(sc.z, v0.z, sh.z), 0.f);
                v0.w = fmaxf(fmaf(sc.w, v0.w, sh.w), 0.f);
                v1.x = fmaxf(fmaf(sc.x, v1.x, sh.x), 0.f);
                v1.y = fmaxf(fmaf(sc.y, v1.y, sh.y), 0.f);
                v1.z = fmaxf(fmaf(sc.z, v1.z, sh.z), 0.f);
                v1.w = fmaxf(fmaf(sc.w, v1.w, sh.w), 0.f);
                v2.x = fmaxf(fmaf(sc.x, v2.x, sh.x), 0.f);
                v2.y = fmaxf(fmaf(sc.y, v2.y, sh.y), 0.f);
                v2.z = fmaxf(fmaf(sc.z, v2.z, sh.z), 0.f);
                v2.w = fmaxf(fmaf(sc.w, v2.w, sh.w), 0.f);
                v3.x = fmaxf(fmaf(sc.x, v3.x, sh.x), 0.f);
                v3.y = fmaxf(fmaf(sc.y, v3.y, sh.y), 0.f);
                v3.z = fmaxf(fmaf(sc.z, v3.z, sh.z), 0.f);
                v3.w = fmaxf(fmaf(sc.w, v3.w, sh.w), 0.f);
            }
            acc.x = fmaf(v0.x, c0, fmaf(v1.x, c1, fmaf(v2.x, c2, fmaf(v3.x, c3, acc.x))));
            acc.y = fmaf(v0.y, c0, fmaf(v1.y, c1, fmaf(v2.y, c2, fmaf(v3.y, c3, acc.y))));
            acc.z = fmaf(v0.z, c0, fmaf(v1.z, c1, fmaf(v2.z, c2, fmaf(v3.z, c3, acc.z))));
            acc.w = fmaf(v0.w, c0, fmaf(v1.w, c1, fmaf(v2.w, c2, fmaf(v3.w, c3, acc.w))));
        }
    }
    part[t] = acc;
    __syncthreads();
    if (half == 0 && slot < NN * 10) {
        const int n = slot / 10, c4 = slot % 10;
        float4 p2 = part[t + 128];
        acc.x += p2.x; acc.y += p2.y; acc.z += p2.z; acc.w += p2.w;
        if (NORM) {
            h4 hv = { (_Float16)acc.x, (_Float16)acc.y, (_Float16)acc.z, (_Float16)acc.w };
            *(h4*)(aggout_h + (size_t)n * 48 + c4 * 4) = hv;
            if (c4 == 0) {   // zero-pad k = 40..47
                h4 zv = { (_Float16)0.f, (_Float16)0.f, (_Float16)0.f, (_Float16)0.f };
                *(h4*)(aggout_h + (size_t)n * 48 + 40) = zv;
                *(h4*)(aggout_h + (size_t)n * 48 + 44) = zv;
            }
        } else {
            ((float4*)aggout_f)[slot] = acc;
        }
    }
}

// ---------------- GraphNorm stats over agg1 (80 blocks, c4-constant stride) ----------------
__global__ __launch_bounds__(256) void k_stats(const float* __restrict__ agg1,
                                               const float* __restrict__ b1,
                                               float* __restrict__ stats) {
    __shared__ float s0[HD], s1[HD];
    if (threadIdx.x < HD) { s0[threadIdx.x] = 0.f; s1[threadIdx.x] = 0.f; }
    __syncthreads();
    const int gid = blockIdx.x * 256 + threadIdx.x;
    const int c4 = gid % 10;          // stride 20480 % 10 == 0 -> constant per thread
    float4 bv = ((const float4*)b1)[c4];
    float4 a0 = make_float4(0.f, 0.f, 0.f, 0.f);
    float4 a1 = a0;
    for (int i4 = gid; i4 < NN * 10; i4 += 80 * 256) {
        float4 v = ((const float4*)agg1)[i4];
        v.x += bv.x; v.y += bv.y; v.z += bv.z; v.w += bv.w;
        a0.x += v.x; a0.y += v.y; a0.z += v.z; a0.w += v.w;
        a1.x = fmaf(v.x, v.x, a1.x);
        a1.y = fmaf(v.y, v.y, a1.y);
        a1.z = fmaf(v.z, v.z, a1.z);
        a1.w = fmaf(v.w, v.w, a1.w);
    }
    atomicAdd(&s0[c4 * 4 + 0], a0.x); atomicAdd(&s0[c4 * 4 + 1], a0.y);
    atomicAdd(&s0[c4 * 4 + 2], a0.z); atomicAdd(&s0[c4 * 4 + 3], a0.w);
    atomicAdd(&s1[c4 * 4 + 0], a1.x); atomicAdd(&s1[c4 * 4 + 1], a1.y);
    atomicAdd(&s1[c4 * 4 + 2], a1.z); atomicAdd(&s1[c4 * 4 + 3], a1.w);
    __syncthreads();
    if (threadIdx.x < HD) {
        atomicAdd(&stats[threadIdx.x], s0[threadIdx.x]);
        atomicAdd(&stats[HD + threadIdx.x], s1[threadIdx.x]);
    }
}

// ---------------- heads via MFMA ----------------
__device__ __forceinline__ float activate_rt(float z, int act) {
    if (act == 0) {                    // mean: clip(exp, 1e-5, 1e6)
        return fminf(fmaxf(__expf(z), 1e-5f), 1e6f);
    } else if (act == 1) {             // disp: clip(softplus, 1e-4, 1e4)
        float sp = fmaxf(z, 0.0f) + __logf(1.0f + __expf(-fabsf(z)));
        return fminf(fmaxf(sp, 1e-4f), 1e4f);
    }
    return __fdividef(1.0f, 1.0f + __expf(-z));   // pi: sigmoid
}

// grid (625, 1, 3); block 256 = 4 waves. Wave wv: rows [bx*16,+16) x cols [wv*128,+128)
// = 8 col-tiles of 16. Per tile: 3x mfma_f32_16x16x16f16 over padded K=48.
// Operand order: W-fragment in A slot -> D reg-dim = columns -> float4 stores.
// A(W) frag: m=col=(lane&15 of tile), k=(lane>>4)*4+j  [pre-swizzled in Whf]
// B(aggh) frag: k=(lane>>4)*4+j, n=row=lane&15
// D: col = tile*16 + (lane>>4)*4 + reg, row = rowbase + (lane&15)
__global__ __launch_bounds__(256) void k_heads3m(const _Float16* __restrict__ agghh,
                                                 const _Float16* __restrict__ Whf,
                                                 const float* __restrict__ bm,
                                                 const float* __restrict__ bd,
                                                 const float* __restrict__ bp,
                                                 float* __restrict__ out) {
    const int z = blockIdx.z;
    const float* bias = (z == 0) ? bm : (z == 1) ? bd : bp;
    float* o = out + (size_t)z * NN * FIN;

    const int lane = threadIdx.x & 63;
    const int wv   = threadIdx.x >> 6;
    const int rowbase = blockIdx.x * 16;
    const int r16  = lane & 15;
    const int kgrp = lane >> 4;

    // aggh (B-slot) fragments: row = rowbase + r16, k = kk*16 + kgrp*4 + j
    const _Float16* arow = agghh + (size_t)(rowbase + r16) * 48 + kgrp * 4;
    h4 g0 = *(const h4*)(arow);
    h4 g1 = *(const h4*)(arow + 16);
    h4 g2 = *(const h4*)(arow + 32);

    const int grow = rowbase + r16;
    float* orow = o + (size_t)grow * FIN;

#pragma unroll
    for (int i = 0; i < 8; ++i) {
        const int ct = wv * 8 + i;               // global col-tile 0..31
        const _Float16* wb = Whf + ((size_t)(z * 32 + ct) * 3) * 256 + lane * 4;
        h4 w0 = *(const h4*)(wb);
        h4 w1 = *(const h4*)(wb + 256);
        h4 w2 = *(const h4*)(wb + 512);
        f4 acc = {0.f, 0.f, 0.f, 0.f};
        acc = __builtin_amdgcn_mfma_f32_16x16x16f16(w0, g0, acc, 0, 0, 0);
        acc = __builtin_amdgcn_mfma_f32_16x16x16f16(w1, g1, acc, 0, 0, 0);
        acc = __builtin_amdgcn_mfma_f32_16x16x16f16(w2, g2, acc, 0, 0, 0);
        const int col0 = ct * 16 + kgrp * 4;     // 4 consecutive cols in regs
        float4 bv = *(const float4*)&bias[col0];
        float4 ov;
        ov.x = activate_rt(acc[0] + bv.x, z);
        ov.y = activate_rt(acc[1] + bv.y, z);
        ov.z = activate_rt(acc[2] + bv.z, z);
        ov.w = activate_rt(acc[3] + bv.w, z);
        *(float4*)(orow + col0) = ov;
    }
}

extern "C" void kernel_launch(void* const* d_in, const int* in_sizes, int n_in,
                              void* d_out, int out_size, void* d_ws, size_t ws_size,
                              hipStream_t stream) {
    const float* x   = (const float*)d_in[0];
    const int*   src = (const int*)d_in[1];
    const int*   dst = (const int*)d_in[2];
    const float* W1  = (const float*)d_in[3];
    const float* b1  = (const float*)d_in[4];
    const float* gnw = (const float*)d_in[5];
    const float* gnb = (const float*)d_in[6];
    const float* gna = (const float*)d_in[7];
    const float* Wm  = (const float*)d_in[8];
    const float* bm  = (const float*)d_in[9];
    const float* Wd  = (const float*)d_in[10];
    const float* bd  = (const float*)d_in[11];
    const float* Wp  = (const float*)d_in[12];
    const float* bp  = (const float*)d_in[13];
    const int E = in_sizes[1];

    // workspace layout: zero-region (cnt,cur,stats) is 16B-aligned by construction
    float*     ws       = (float*)d_ws;
    float*     h1       = ws;                          // NN*HD f32 (mm1 out; agghh f16 reuses this space later)
    float*     agg1     = h1 + (size_t)NN * HD;        // NN*HD  (gather1 out)
    int*       cnt      = (int*)(agg1 + (size_t)NN * HD);  // NN   } zeroed (int4)
    int*       cur      = cnt + NN;                    // NN     } zeroed
    float*     stats    = (float*)(cur + NN);          // 2*HD   } zeroed
    float*     dis      = stats + 2 * HD;              // NN
    int*       rowstart = (int*)(dis + NN);            // NN+1 (+1 pad for int2 align)
    int2*      csr      = (int2*)(rowstart + NN + 2);  // E int2, 8B-aligned
    _Float16*  Whf      = (_Float16*)(csr + E);        // 3*32*3*256 f16 (144 KB)
    _Float16*  agghh    = (_Float16*)h1;               // NN*48 f16 = 960 KB < NN*HD*4
    float*     out      = (float*)d_out;

    k_cvtW<<<(3 * 32 * 3 * 64 + 255) / 256, 256, 0, stream>>>(Wm, Wd, Wp, Whf);
    // mm1 + zero fused (zero blocks ride along; cnt zeroed before k_hist runs)
    k_mm1z<<<MM1_BLOCKS + ZERO_BLOCKS, 256, 0, stream>>>(x, W1, h1, (int4*)cnt);
    k_hist<<<(E + 255) / 256, 256, 0, stream>>>(dst, cnt, E);
    k_scan<<<1, 1024, 0, stream>>>(cnt, rowstart, dis);
    k_fill<<<(E + 255) / 256, 256, 0, stream>>>(src, dst, rowstart, cur, dis, csr, E);
    const int gblocks = (NN * 10 + 127) / 128;
    k_gather<false><<<gblocks, 256, 0, stream>>>(rowstart, csr, h1, nullptr,
                                                 nullptr, nullptr, nullptr, nullptr,
                                                 agg1, nullptr);
    k_stats<<<80, 256, 0, stream>>>(agg1, b1, stats);
    // reads agg1 (f32), writes f16 padded aggh into h1's (dead) buffer
    k_gather<true><<<gblocks, 256, 0, stream>>>(rowstart, csr, agg1, stats,
                                                b1, gnw, gnb, gna,
                                                nullptr, agghh);
    dim3 hgrid(MM1_BLOCKS, 1, 3);
    k_heads3m<<<hgrid, 256, 0, stream>>>(agghh, Whf, bm, bd, bp, out);
}

// Round 14
// 110.333 us; speedup vs baseline: 1.6401x; 1.0904x over previous
//
#include <hip/hip_runtime.h>
#include <math.h>

#define NN 10000
#define FIN 512
#define HD 40
#define GEPS 1e-5f

#define ZI4 ((2 * NN + 2 * HD) / 4)       // 5020 int4s (cnt, cur, stats)
#define MM1_BLOCKS ((NN + 15) / 16)       // 625
#define ZERO_BLOCKS ((ZI4 + 255) / 256)   // 20
#define CVT_BLOCKS ((3 * 32 * 3 * 64 + 255) / 256)   // 72

typedef _Float16 h4 __attribute__((ext_vector_type(4)));
typedef float f4 __attribute__((ext_vector_type(4)));

// ---------------- CSR build ----------------
__global__ void k_hist(const int* __restrict__ dst, int* __restrict__ cnt, int E) {
    int e = blockIdx.x * blockDim.x + threadIdx.x;
    if (e < E) atomicAdd(&cnt[dst[e]], 1);
}

// single block, 1024 threads; 16 rows/thread (625*16 == NN exactly);
// int4 loads + int4/float4 stores; fused dis=rsqrt(deg)
__global__ __launch_bounds__(1024) void k_scan(const int* __restrict__ cnt,
                                               int* __restrict__ rowstart,
                                               float* __restrict__ dis) {
    __shared__ int lds[1024];
    const int t = threadIdx.x;
    const int start = t * 16;
    int4 c[4];
    int s = 0;
    if (start < NN) {
#pragma unroll
        for (int q = 0; q < 4; ++q) {
            c[q] = *(const int4*)(cnt + start + q * 4);
            s += c[q].x + c[q].y + c[q].z + c[q].w;
        }
    }
    lds[t] = s;
    __syncthreads();
    for (int off = 1; off < 1024; off <<= 1) {
        int v = (t >= off) ? lds[t - off] : 0;
        __syncthreads();
        lds[t] += v;
        __syncthreads();
    }
    if (start < NN) {
        int run = lds[t] - s;   // exclusive prefix
#pragma unroll
        for (int q = 0; q < 4; ++q) {
            int4 rs; float4 dv;
            rs.x = run; dv.x = rsqrtf((float)c[q].x); run += c[q].x;
            rs.y = run; dv.y = rsqrtf((float)c[q].y); run += c[q].y;
            rs.z = run; dv.z = rsqrtf((float)c[q].z); run += c[q].z;
            rs.w = run; dv.w = rsqrtf((float)c[q].w); run += c[q].w;
            *(int4*)(rowstart + start + q * 4) = rs;
            *(float4*)(dis + start + q * 4) = dv;
        }
        if (start + 16 == NN) rowstart[NN] = run;
    }
}

__global__ void k_fill(const int* __restrict__ src, const int* __restrict__ dst,
                       const int* __restrict__ rowstart, int* __restrict__ cur,
                       const float* __restrict__ dis, int2* __restrict__ csr, int E) {
    int e = blockIdx.x * blockDim.x + threadIdx.x;
    if (e >= E) return;
    int s = src[e], d = dst[e];
    int pos = rowstart[d] + atomicAdd(&cur[d], 1);
    int2 v;
    v.x = s;
    v.y = __float_as_int(dis[s] * dis[d]);
    csr[pos] = v;
}

// ---------------- h1 = x @ W1 ; side blocks: zero cnt/cur/stats + cvt W->fp16 frags ----------------
// Whf[((z*32+ct)*3+kk)*64 + lane][j] = (k<40 ? W_z[k][ct*16+(lane&15)] : 0),
// k = kk*16 + (lane>>4)*4 + j   (fragment order for mfma_f32_16x16x16f16)
__global__ __launch_bounds__(256) void k_mm1z(const float* __restrict__ x,
                                              const float* __restrict__ W1,
                                              float* __restrict__ h1,
                                              int4* __restrict__ zbuf,
                                              const float* __restrict__ Wm,
                                              const float* __restrict__ Wd,
                                              const float* __restrict__ Wp,
                                              _Float16* __restrict__ Whf) {
    if (blockIdx.x >= MM1_BLOCKS + ZERO_BLOCKS) {   // cvtW-duty blocks
        int idx = (blockIdx.x - MM1_BLOCKS - ZERO_BLOCKS) * 256 + threadIdx.x;
        if (idx < 3 * 32 * 3 * 64) {
            int lane = idx & 63;
            int kk   = (idx >> 6) % 3;
            int ct   = ((idx >> 6) / 3) % 32;
            int z    = idx / (64 * 3 * 32);
            const float* W = (z == 0) ? Wm : (z == 1) ? Wd : Wp;
            int col = ct * 16 + (lane & 15);
            h4 v;
#pragma unroll
            for (int j = 0; j < 4; ++j) {
                int krow = kk * 16 + (lane >> 4) * 4 + j;
                v[j] = (krow < HD) ? (_Float16)W[(size_t)krow * FIN + col] : (_Float16)0.f;
            }
            *(h4*)(Whf + (size_t)idx * 4) = v;
        }
        return;
    }
    if (blockIdx.x >= MM1_BLOCKS) {       // zero-duty blocks
        int i = (blockIdx.x - MM1_BLOCKS) * 256 + threadIdx.x;
        if (i < ZI4) zbuf[i] = make_int4(0, 0, 0, 0);
        return;
    }
    __shared__ float red[256 * 41];       // 41-pad: odd stride -> conflict-free
    const int tid = threadIdx.x;
    const int r = tid & 15;
    const int kg = tid >> 4;              // 0..15, 32 k each
    const int row = blockIdx.x * 16 + r;
    const int rowc = min(row, NN - 1);
    const float4* xr = (const float4*)(x + (size_t)rowc * FIN + kg * 32);
    float acc[HD];
#pragma unroll
    for (int c = 0; c < HD; ++c) acc[c] = 0.f;
#pragma unroll 2
    for (int q = 0; q < 8; ++q) {
        float4 xv = xr[q];
        const float* wbase = W1 + (size_t)(kg * 32 + q * 4) * HD;
#pragma unroll
        for (int kk = 0; kk < 4; ++kk) {
            float xs = (kk == 0) ? xv.x : (kk == 1) ? xv.y : (kk == 2) ? xv.z : xv.w;
#pragma unroll
            for (int c4 = 0; c4 < 10; ++c4) {
                float4 wv = *(const float4*)(wbase + kk * HD + c4 * 4);
                acc[c4 * 4 + 0] = fmaf(xs, wv.x, acc[c4 * 4 + 0]);
                acc[c4 * 4 + 1] = fmaf(xs, wv.y, acc[c4 * 4 + 1]);
                acc[c4 * 4 + 2] = fmaf(xs, wv.z, acc[c4 * 4 + 2]);
                acc[c4 * 4 + 3] = fmaf(xs, wv.w, acc[c4 * 4 + 3]);
            }
        }
    }
#pragma unroll
    for (int c = 0; c < HD; ++c) red[tid * 41 + c] = acc[c];
    __syncthreads();
    if (tid < 160) {                      // 16 rows x 10 float4
        int rr = tid / 10, c4 = tid % 10;
        float o0 = 0.f, o1 = 0.f, o2 = 0.f, o3 = 0.f;
#pragma unroll
        for (int kg2 = 0; kg2 < 16; ++kg2) {
            const float* p = &red[(kg2 * 16 + rr) * 41 + c4 * 4];
            o0 += p[0]; o1 += p[1]; o2 += p[2]; o3 += p[3];
        }
        int orow = blockIdx.x * 16 + rr;
        if (orow < NN)
            *(float4*)&h1[(size_t)orow * HD + c4 * 4] = make_float4(o0, o1, o2, o3);
    }
}

// ---------------- gather: out[n] = sum coef * f(hin[src]) ----------------
// 2 threads per (node,c4) slot (contiguous half ranges), 8 edges in flight
// (avg 8.5 edges/half -> ~1 latency-exposed round). Clamp+mask tail.
// !NORM: writes f32 agg. NORM: relu(sc*v+sh), writes f16 [NN][48] (k 40..47 zero).
template <bool NORM>
__global__ __launch_bounds__(256) void k_gather(const int* __restrict__ rowstart,
                                                const int2* __restrict__ csr,
                                                const float* __restrict__ hin,
                                                const float* __restrict__ stats,
                                                const float* __restrict__ b1,
                                                const float* __restrict__ gw,
                                                const float* __restrict__ gb,
                                                const float* __restrict__ ga,
                                                float* __restrict__ aggout_f,
                                                _Float16* __restrict__ aggout_h) {
    __shared__ float4 part[256];
    __shared__ float csc[2 * HD];
    const int t = threadIdx.x;
    if (NORM) {
        if (t < HD) {
            float m   = stats[t] * (1.0f / NN);
            float ex2 = stats[HD + t] * (1.0f / NN);
            float a   = ga[t];
            float var = ex2 - 2.0f * a * m * m + a * a * m * m;
            float sc  = gw[t] * rsqrtf(var + GEPS);
            csc[t]      = sc;
            csc[HD + t] = sc * (b1[t] - a * m) + gb[t];
        }
        __syncthreads();
    }
    const int slot = blockIdx.x * 128 + (t & 127);
    const int half = t >> 7;
    float4 acc = make_float4(0.f, 0.f, 0.f, 0.f);
    if (slot < NN * 10) {
        const int n = slot / 10, c4 = slot % 10;
        const int j0 = rowstart[n], j1 = rowstart[n + 1];
        const int mid = j0 + ((j1 - j0 + 1) >> 1);
        const int ja = half ? mid : j0;
        const int jb = half ? j1 : mid;
        float4 sc, sh;
        if (NORM) {
            sc = ((const float4*)csc)[c4];
            sh = ((const float4*)csc)[10 + c4];
        }
        for (int j = ja; j < jb; j += 8) {
            const int jm = jb - 1;
            int2 e[8];
#pragma unroll
            for (int q = 0; q < 8; ++q) e[q] = csr[min(j + q, jm)];
            float4 v[8];
#pragma unroll
            for (int q = 0; q < 8; ++q)
                v[q] = *(const float4*)&hin[(size_t)e[q].x * HD + c4 * 4];
#pragma unroll
            for (int q = 0; q < 8; ++q) {
                float cf = (j + q < jb) ? __int_as_float(e[q].y) : 0.f;
                if (NORM) {
                    v[q].x = fmaxf(fmaf(sc.x, v[q].x, sh.x), 0.f);
                    v[q].y = fmaxf(fmaf(sc.y, v[q].y, sh.y), 0.f);
                    v[q].z = fmaxf(fmaf(sc.z, v[q].z, sh.z), 0.f);
                    v[q].w = fmaxf(fmaf(sc.w, v[q].w, sh.w), 0.f);
                }
                acc.x = fmaf(v[q].x, cf, acc.x);
                acc.y = fmaf(v[q].y, cf, acc.y);
                acc.z = fmaf(v[q].z, cf, acc.z);
                acc.w = fmaf(v[q].w, cf, acc.w);
            }
        }
    }
    part[t] = acc;
    __syncthreads();
    if (half == 0 && slot < NN * 10) {
        const int n = slot / 10, c4 = slot % 10;
        float4 p2 = part[t + 128];
        acc.x += p2.x; acc.y += p2.y; acc.z += p2.z; acc.w += p2.w;
        if (NORM) {
            h4 hv = { (_Float16)acc.x, (_Float16)acc.y, (_Float16)acc.z, (_Float16)acc.w };
            *(h4*)(aggout_h + (size_t)n * 48 + c4 * 4) = hv;
            if (c4 == 0) {   // zero-pad k = 40..47
                h4 zv = { (_Float16)0.f, (_Float16)0.f, (_Float16)0.f, (_Float16)0.f };
                *(h4*)(aggout_h + (size_t)n * 48 + 40) = zv;
                *(h4*)(aggout_h + (size_t)n * 48 + 44) = zv;
            }
        } else {
            ((float4*)aggout_f)[slot] = acc;
        }
    }
}

// ---------------- GraphNorm stats over agg1 (80 blocks, c4-constant stride) ----------------
__global__ __launch_bounds__(256) void k_stats(const float* __restrict__ agg1,
                                               const float* __restrict__ b1,
                                               float* __restrict__ stats) {
    __shared__ float s0[HD], s1[HD];
    if (threadIdx.x < HD) { s0[threadIdx.x] = 0.f; s1[threadIdx.x] = 0.f; }
    __syncthreads();
    const int gid = blockIdx.x * 256 + threadIdx.x;
    const int c4 = gid % 10;          // stride 20480 % 10 == 0 -> constant per thread
    float4 bv = ((const float4*)b1)[c4];
    float4 a0 = make_float4(0.f, 0.f, 0.f, 0.f);
    float4 a1 = a0;
    for (int i4 = gid; i4 < NN * 10; i4 += 80 * 256) {
        float4 v = ((const float4*)agg1)[i4];
        v.x += bv.x; v.y += bv.y; v.z += bv.z; v.w += bv.w;
        a0.x += v.x; a0.y += v.y; a0.z += v.z; a0.w += v.w;
        a1.x = fmaf(v.x, v.x, a1.x);
        a1.y = fmaf(v.y, v.y, a1.y);
        a1.z = fmaf(v.z, v.z, a1.z);
        a1.w = fmaf(v.w, v.w, a1.w);
    }
    atomicAdd(&s0[c4 * 4 + 0], a0.x); atomicAdd(&s0[c4 * 4 + 1], a0.y);
    atomicAdd(&s0[c4 * 4 + 2], a0.z); atomicAdd(&s0[c4 * 4 + 3], a0.w);
    atomicAdd(&s1[c4 * 4 + 0], a1.x); atomicAdd(&s1[c4 * 4 + 1], a1.y);
    atomicAdd(&s1[c4 * 4 + 2], a1.z); atomicAdd(&s1[c4 * 4 + 3], a1.w);
    __syncthreads();
    if (threadIdx.x < HD) {
        atomicAdd(&stats[threadIdx.x], s0[threadIdx.x]);
        atomicAdd(&stats[HD + threadIdx.x], s1[threadIdx.x]);
    }
}

// ---------------- heads via MFMA ----------------
__device__ __forceinline__ float activate_rt(float z, int act) {
    if (act == 0) {                    // mean: clip(exp, 1e-5, 1e6)
        return fminf(fmaxf(__expf(z), 1e-5f), 1e6f);
    } else if (act == 1) {             // disp: clip(softplus, 1e-4, 1e4)
        float sp = fmaxf(z, 0.0f) + __logf(1.0f + __expf(-fabsf(z)));
        return fminf(fmaxf(sp, 1e-4f), 1e4f);
    }
    return __fdividef(1.0f, 1.0f + __expf(-z));   // pi: sigmoid
}

// grid (625, 1, 3); block 256 = 4 waves. Wave wv: rows [bx*16,+16) x cols [wv*128,+128)
// = 8 col-tiles of 16. Per tile: 3x mfma_f32_16x16x16f16 over padded K=48.
// W-fragment in A slot -> D reg-dim = columns -> float4 stores.
__global__ __launch_bounds__(256) void k_heads3m(const _Float16* __restrict__ agghh,
                                                 const _Float16* __restrict__ Whf,
                                                 const float* __restrict__ bm,
                                                 const float* __restrict__ bd,
                                                 const float* __restrict__ bp,
                                                 float* __restrict__ out) {
    const int z = blockIdx.z;
    const float* bias = (z == 0) ? bm : (z == 1) ? bd : bp;
    float* o = out + (size_t)z * NN * FIN;

    const int lane = threadIdx.x & 63;
    const int wv   = threadIdx.x >> 6;
    const int rowbase = blockIdx.x * 16;
    const int r16  = lane & 15;
    const int kgrp = lane >> 4;

    // aggh (B-slot) fragments: row = rowbase + r16, k = kk*16 + kgrp*4 + j
    const _Float16* arow = agghh + (size_t)(rowbase + r16) * 48 + kgrp * 4;
    h4 g0 = *(const h4*)(arow);
    h4 g1 = *(const h4*)(arow + 16);
    h4 g2 = *(const h4*)(arow + 32);

    const int grow = rowbase + r16;
    float* orow = o + (size_t)grow * FIN;

#pragma unroll
    for (int i = 0; i < 8; ++i) {
        const int ct = wv * 8 + i;               // global col-tile 0..31
        const _Float16* wb = Whf + ((size_t)(z * 32 + ct) * 3) * 256 + lane * 4;
        h4 w0 = *(const h4*)(wb);
        h4 w1 = *(const h4*)(wb + 256);
        h4 w2 = *(const h4*)(wb + 512);
        f4 acc = {0.f, 0.f, 0.f, 0.f};
        acc = __builtin_amdgcn_mfma_f32_16x16x16f16(w0, g0, acc, 0, 0, 0);
        acc = __builtin_amdgcn_mfma_f32_16x16x16f16(w1, g1, acc, 0, 0, 0);
        acc = __builtin_amdgcn_mfma_f32_16x16x16f16(w2, g2, acc, 0, 0, 0);
        const int col0 = ct * 16 + kgrp * 4;     // 4 consecutive cols in regs
        float4 bv = *(const float4*)&bias[col0];
        float4 ov;
        ov.x = activate_rt(acc[0] + bv.x, z);
        ov.y = activate_rt(acc[1] + bv.y, z);
        ov.z = activate_rt(acc[2] + bv.z, z);
        ov.w = activate_rt(acc[3] + bv.w, z);
        *(float4*)(orow + col0) = ov;
    }
}

extern "C" void kernel_launch(void* const* d_in, const int* in_sizes, int n_in,
                              void* d_out, int out_size, void* d_ws, size_t ws_size,
                              hipStream_t stream) {
    const float* x   = (const float*)d_in[0];
    const int*   src = (const int*)d_in[1];
    const int*   dst = (const int*)d_in[2];
    const float* W1  = (const float*)d_in[3];
    const float* b1  = (const float*)d_in[4];
    const float* gnw = (const float*)d_in[5];
    const float* gnb = (const float*)d_in[6];
    const float* gna = (const float*)d_in[7];
    const float* Wm  = (const float*)d_in[8];
    const float* bm  = (const float*)d_in[9];
    const float* Wd  = (const float*)d_in[10];
    const float* bd  = (const float*)d_in[11];
    const float* Wp  = (const float*)d_in[12];
    const float* bp  = (const float*)d_in[13];
    const int E = in_sizes[1];

    // workspace layout: zero-region (cnt,cur,stats) is 16B-aligned by construction
    float*     ws       = (float*)d_ws;
    float*     h1       = ws;                          // NN*HD f32 (mm1 out; agghh f16 reuses later)
    float*     agg1     = h1 + (size_t)NN * HD;        // NN*HD  (gather1 out)
    int*       cnt      = (int*)(agg1 + (size_t)NN * HD);  // NN   } zeroed (int4)
    int*       cur      = cnt + NN;                    // NN     } zeroed
    float*     stats    = (float*)(cur + NN);          // 2*HD   } zeroed
    float*     dis      = stats + 2 * HD;              // NN
    int*       rowstart = (int*)(dis + NN);            // NN+1 (+1 pad for int2 align)
    int2*      csr      = (int2*)(rowstart + NN + 2);  // E int2, 8B-aligned
    _Float16*  Whf      = (_Float16*)(csr + E);        // 3*32*3*256 f16 (144 KB)
    _Float16*  agghh    = (_Float16*)h1;               // NN*48 f16 = 960 KB < NN*HD*4
    float*     out      = (float*)d_out;

    // mm1 + zero + cvtW fused (side blocks ride along)
    k_mm1z<<<MM1_BLOCKS + ZERO_BLOCKS + CVT_BLOCKS, 256, 0, stream>>>(
        x, W1, h1, (int4*)cnt, Wm, Wd, Wp, Whf);
    k_hist<<<(E + 255) / 256, 256, 0, stream>>>(dst, cnt, E);
    k_scan<<<1, 1024, 0, stream>>>(cnt, rowstart, dis);
    k_fill<<<(E + 255) / 256, 256, 0, stream>>>(src, dst, rowstart, cur, dis, csr, E);
    const int gblocks = (NN * 10 + 127) / 128;
    k_gather<false><<<gblocks, 256, 0, stream>>>(rowstart, csr, h1, nullptr,
                                                 nullptr, nullptr, nullptr, nullptr,
                                                 agg1, nullptr);
    k_stats<<<80, 256, 0, stream>>>(agg1, b1, stats);
    // reads agg1 (f32), writes f16 padded aggh into h1's (dead) buffer
    k_gather<true><<<gblocks, 256, 0, stream>>>(rowstart, csr, agg1, stats,
                                                b1, gnw, gnb, gna,
                                                nullptr, agghh);
    dim3 hgrid(MM1_BLOCKS, 1, 3);
    k_heads3m<<<hgrid, 256, 0, stream>>>(agghh, Whf, bm, bd, bp, out);
}